// Round 9
// baseline (1193.281 us; speedup 1.0000x reference)
//
#include <hip/hip_runtime.h>
#include <hip/hip_bf16.h>

typedef unsigned short u16;
typedef unsigned int u32;
typedef short short8v __attribute__((ext_vector_type(8)));
typedef float f32x4 __attribute__((ext_vector_type(4)));

#define NN 50000
#define EE 800000
#define PP 65536
#define NB 196  // ceil(NN/256)

// ---- static device workspace. RULE (r3): device-global addresses never cross
// the host/device boundary — kernels resolve them via compile-time IDs.
__device__ __align__(256) float g_deg_norm[NN];
__device__ __align__(256) int   g_row_ptr[NN + 1];
__device__ __align__(256) int   g_deg[NN];
__device__ __align__(256) int   g_rank[EE];        // intra-row rank from count_deg
__device__ __align__(256) int   g_bsum[256];
__device__ __align__(256) int   g_boff[256];
__device__ __align__(256) int2  g_ecw[EE];         // (col, w-bits) fused pair
__device__ __align__(256) u16   g_X16[NN * 128];   // x pre-converted to bf16
__device__ __align__(256) u16   g_H1[NN * 128];    // hop outputs, stride 128
__device__ __align__(256) u16   g_H2[NN * 128];
__device__ __align__(256) u16   g_H3[NN * 128];
__device__ __align__(256) u16   g_Hn0[NN * 128];
__device__ __align__(256) u16   g_Hn1[NN * 128];
__device__ __align__(256) u16   g_Hf16[NN * 64];   // final h (bf16) for predictor
__device__ __align__(256) u16   g_Bf1[512 * 128];  // W in MFMA B-fragment order
__device__ __align__(256) u16   g_Bf2[512 * 128];
__device__ __align__(256) u16   g_Bf3[512 * 64];
__device__ int g_f32mode;  // 1 if harness float tensors are float32, 0 if bf16

__device__ __forceinline__ float bf2f(u16 u) {
  union { u32 i; float f; } v;
  v.i = ((u32)u) << 16;
  return v.f;
}
__device__ __forceinline__ u16 f2bf(float f) {
  u32 x = __float_as_uint(f);
  u32 r = (x + 0x7fffu + ((x >> 16) & 1u)) >> 16;  // RNE
  return (u16)r;
}
__device__ __forceinline__ float ldf(const void* p, int i, int m) {
  return m ? ((const float*)p)[i] : bf2f(((const u16*)p)[i]);
}

// buffer IDs: 0 = X16, 3 = Hn0, 4 = Hn1, 5 = H1, 6 = H2, 7 = H3 (all stride 128)
template <int ID>
__device__ __forceinline__ u16* sel_buf() {
  if (ID == 0) return g_X16;
  if (ID == 3) return g_Hn0;
  if (ID == 4) return g_Hn1;
  if (ID == 5) return g_H1;
  if (ID == 6) return g_H2;
  return g_H3;
}
template <int ID>
__device__ __forceinline__ u16* sel_bf() {
  if (ID == 1) return g_Bf1;
  if (ID == 2) return g_Bf2;
  return g_Bf3;
}

// -------------------------------------------------------------- dtype probe
__global__ void probe_dtype_kernel(const u16* __restrict__ x) {
  __shared__ int cnt;
  if (threadIdx.x == 0) cnt = 0;
  __syncthreads();
  int c = 0;
  for (int i = threadIdx.x; i < 2048; i += 256) {
    u16 u = x[2 * i];
    int e = (u >> 7) & 0xFF;
    if (e >= 0x8F) c++;
  }
  atomicAdd(&cnt, c);
  __syncthreads();
  if (threadIdx.x == 0) g_f32mode = (cnt > 64) ? 1 : 0;
}

// ---------------------------------------------------------- x -> bf16 convert
__global__ void convert_x_kernel(const void* __restrict__ x) {
  int m = g_f32mode;
  int i = blockIdx.x * 256 + threadIdx.x;  // u32-pair index
  if (i >= NN * 64) return;
  u32 lo = f2bf(ldf(x, 2 * i, m));
  u32 hi = f2bf(ldf(x, 2 * i + 1, m));
  ((u32*)g_X16)[i] = lo | (hi << 16);
}

// --------------------------------------------- W -> fragment-ordered bf16
template <int FOUT, int BF_ID>
__global__ void convert_w_kernel(const void* __restrict__ W) {
  constexpr int NT = FOUT / 16;
  int m = g_f32mode;
  int t = blockIdx.x * 256 + threadIdx.x;
  if (t >= 1024 * NT) return;
  int lane = t & 63;
  int rest = t >> 6;
  int nt = rest % NT;
  int s = (rest / NT) % 4;
  int kc = rest / (NT * 4);
  int kbase = kc * 128 + s * 32 + ((lane >> 4) << 3);
  int n = nt * 16 + (lane & 15);
  u16* dst = sel_bf<BF_ID>() + (size_t)t * 8;
#pragma unroll
  for (int j = 0; j < 8; ++j) dst[j] = f2bf(ldf(W, (kbase + j) * FOUT + n, m));
}

// ---------------------------------------------------------------- CSR build
__global__ void zero_deg_kernel() {
  int i = blockIdx.x * blockDim.x + threadIdx.x;
  if (i < NN) g_deg[i] = 0;
}
// atomic return value IS the intra-row rank -> store it (coalesced), so
// fill_csr needs no atomic.
__global__ void count_deg_kernel(const int* __restrict__ dst) {
  int e = blockIdx.x * blockDim.x + threadIdx.x;
  if (e < EE) g_rank[e] = atomicAdd(&g_deg[dst[e]], 1);
}
__global__ __launch_bounds__(256) void deg_partial_kernel() {
  __shared__ int ws[4];
  int b = blockIdx.x, t = threadIdx.x;
  int i = b * 256 + t;
  int v = (i < NN) ? g_deg[i] : 0;
  if (i < NN) g_deg_norm[i] = rsqrtf((float)(v > 0 ? v : 1));
  int x = v;
#pragma unroll
  for (int off = 1; off < 64; off <<= 1) x += __shfl_xor(x, off, 64);
  if ((t & 63) == 0) ws[t >> 6] = x;
  __syncthreads();
  if (t == 0) g_bsum[b] = ws[0] + ws[1] + ws[2] + ws[3];
}
__global__ __launch_bounds__(256) void scan_bsum_kernel() {
  __shared__ int ws[4];
  int t = threadIdx.x;
  int v = (t < NB) ? g_bsum[t] : 0;
  int x = v;
#pragma unroll
  for (int off = 1; off < 64; off <<= 1) {
    int y = __shfl_up(x, off, 64);
    if ((t & 63) >= off) x += y;
  }
  if ((t & 63) == 63) ws[t >> 6] = x;
  __syncthreads();
  int wp = 0;
  if (t >= 64) wp += ws[0];
  if (t >= 128) wp += ws[1];
  if (t >= 192) wp += ws[2];
  if (t < NB) g_boff[t] = wp + x - v;  // exclusive
}
__global__ __launch_bounds__(256) void rowptr_kernel() {
  __shared__ int ws[4];
  int b = blockIdx.x, t = threadIdx.x;
  int i = b * 256 + t;
  int v = (i < NN) ? g_deg[i] : 0;
  int x = v;
#pragma unroll
  for (int off = 1; off < 64; off <<= 1) {
    int y = __shfl_up(x, off, 64);
    if ((t & 63) >= off) x += y;
  }
  if ((t & 63) == 63) ws[t >> 6] = x;
  __syncthreads();
  int wp = g_boff[b];
  if (t >= 64) wp += ws[0];
  if (t >= 128) wp += ws[1];
  if (t >= 192) wp += ws[2];
  if (i < NN) g_row_ptr[i] = wp + x - v;
  if (b == 0 && t == 0) g_row_ptr[NN] = EE;
}
__global__ void fill_csr_kernel(const int* __restrict__ src, const int* __restrict__ dst,
                                const void* __restrict__ w_edge) {
  int m = g_f32mode;
  int e = blockIdx.x * blockDim.x + threadIdx.x;
  if (e >= EE) return;
  int d = dst[e], s = src[e];
  int slot = g_row_ptr[d] + g_rank[e];  // no atomic
  float w = ldf(w_edge, e, m) * g_deg_norm[s];
  g_ecw[slot] = make_int2(s, __float_as_int(w));
}

// ------------------------------------------------------------------- one hop
// out[n][f] = deg_norm[n] * sum_e w[e] * in[col[e]][f]
// PHASE-MAJOR feature chunking (r8 post-mortem): chunk = blockIdx/6250, so the
// whole GPU processes one 3.2-MB feature slice at a time -> every XCD's L2
// holds the (replicated) slice; no workgroup->XCD mapping assumption. Edge
// stream is re-read per phase but loaded NON-TEMPORALLY so it cannot evict the
// slice. Half-wave (32 lanes x u16) per node per chunk = one 64-B line per
// edge-gather. Output stored non-temporally (consumed cross-XCD next hop).
template <int IN_ID, int OUT_ID>
__global__ __launch_bounds__(256) void hop_kernel() {
  int bi = blockIdx.x;           // 25000 blocks = 4 phases x 6250
  int chunk = bi / 6250;         // phase-major: consecutive blocks share chunk
  int g = bi - chunk * 6250;
  int tid = threadIdx.x;
  int hw = tid >> 5;             // half-wave 0..7
  int l = tid & 31;
  int n = g * 8 + hw;            // 6250*8 = 50000 exactly
  const u16* in = sel_buf<IN_ID>() + chunk * 32 + l;
  int beg = g_row_ptr[n], end = g_row_ptr[n + 1];
  float a[8];
#pragma unroll
  for (int i = 0; i < 8; ++i) a[i] = 0.f;
  int e = beg;
  for (; e + 8 <= end; e += 8) {
    u32 pw = __builtin_nontemporal_load((const u32*)(g_ecw + e) + (l & 15));
#pragma unroll
    for (int i = 0; i < 8; ++i) {
      int si = __shfl((int)pw, 2 * i, 16);
      float wi = __int_as_float(__shfl((int)pw, 2 * i + 1, 16));
      a[i] += wi * bf2f(in[si * 128]);
    }
  }
  for (; e < end; ++e) {
    int2 p = g_ecw[e];
    a[0] += __int_as_float(p.y) * bf2f(in[p.x * 128]);
  }
  float s = ((a[0] + a[1]) + (a[2] + a[3])) + ((a[4] + a[5]) + (a[6] + a[7]));
  u16 r = f2bf(s * g_deg_norm[n]);
  __builtin_nontemporal_store(r, sel_buf<OUT_ID>() + n * 128 + chunk * 32 + l);
}

// ------------------------------------------------------------------ MFMA GEMM
// C(M x FOUT) = [f0 | H1 | H2 | H3] (Mx512, all stride 128) @ B + bias, opt ReLU.
// Block = 128 rows x ALL FOUT cols (A read exactly once). 4 waves x 32 rows.
template <int FOUT, bool RELU, int A0_ID, int C_ID, int BF_ID>
__global__ __launch_bounds__(256) void gemm_kernel(const void* __restrict__ bias,
                                                   void* __restrict__ outp) {
  constexpr int NT = FOUT / 16;
  const u16* Bf = sel_bf<BF_ID>();
  int tid = threadIdx.x;
  int lane = tid & 63, wv = tid >> 6;
  int quad = lane >> 4, arow = lane & 15;
  int mbase = blockIdx.x * 128 + wv * 32;
  bool gu0 = mbase < NN;
  bool gu1 = (mbase + 16) < NN;
  if (!gu0) return;  // no barriers in kernel -> safe
  int row0 = mbase + arow, row1 = mbase + 16 + arow;

  f32x4 acc[2][NT];
#pragma unroll
  for (int mt = 0; mt < 2; ++mt)
#pragma unroll
    for (int nt = 0; nt < NT; ++nt) acc[mt][nt] = (f32x4){0.f, 0.f, 0.f, 0.f};

#pragma unroll
  for (int kc = 0; kc < 4; ++kc) {
    const u16* base = (kc == 0) ? sel_buf<A0_ID>() : (kc == 1) ? g_H1 : (kc == 2) ? g_H2 : g_H3;
#pragma unroll
    for (int s = 0; s < 4; ++s) {
      int ko = s * 32 + quad * 8;
      short8v av0 = *(const short8v*)(base + row0 * 128 + ko);
      short8v av1;
      if (gu1) av1 = *(const short8v*)(base + row1 * 128 + ko);
      const u16* bp = Bf + (size_t)(((kc * 4 + s) * NT) * 64 + lane) * 8;
#pragma unroll
      for (int nt = 0; nt < NT; ++nt) {
        short8v b = *(const short8v*)(bp + nt * 64 * 8);
        acc[0][nt] = __builtin_amdgcn_mfma_f32_16x16x32_bf16(av0, b, acc[0][nt], 0, 0, 0);
        if (gu1) acc[1][nt] = __builtin_amdgcn_mfma_f32_16x16x32_bf16(av1, b, acc[1][nt], 0, 0, 0);
      }
    }
  }

  int m = g_f32mode;
  float bn[NT];
#pragma unroll
  for (int nt = 0; nt < NT; ++nt) bn[nt] = ldf(bias, nt * 16 + arow, m);
#pragma unroll
  for (int mt = 0; mt < 2; ++mt) {
    if (mt == 1 && !gu1) break;
#pragma unroll
    for (int i = 0; i < 4; ++i) {
      int row = mbase + mt * 16 + quad * 4 + i;  // C/D: col=lane&15, row=quad*4+reg
#pragma unroll
      for (int nt = 0; nt < NT; ++nt) {
        float v = acc[mt][nt][i] + bn[nt];
        if (RELU) v = v > 0.f ? v : 0.f;
        int ci = row * FOUT + nt * 16 + arow;
        if (C_ID == 0) {
          g_Hf16[ci] = f2bf(v);
          if (m) ((float*)outp)[2 * PP + ci] = v;
          else   ((u16*)outp)[2 * PP + ci] = f2bf(v);
        } else {
          sel_buf<C_ID>()[ci] = f2bf(v);
        }
      }
    }
  }
}

// ------------------------------------------------------------------ predictor
// k-outer accumulation: no z[64] register array (r7: VGPR 140 -> occupancy 10%).
__global__ __launch_bounds__(256) void predictor_kernel(
    const int* __restrict__ pos_src, const int* __restrict__ pos_dst,
    const int* __restrict__ neg_src, const int* __restrict__ neg_dst,
    const void* __restrict__ P1, const void* __restrict__ pb1, const void* __restrict__ P2,
    const void* __restrict__ pb2, const void* __restrict__ P3, const void* __restrict__ pb3,
    void* __restrict__ out) {
  __shared__ float sP1[64 * 32];
  __shared__ float sP2[32 * 16];
  __shared__ float sP3[16];
  __shared__ float sb1[32], sb2[16], sb3;
  int m = g_f32mode;
  int tid = threadIdx.x;
  for (int i = tid; i < 64 * 32; i += 256) sP1[i] = ldf(P1, i, m);
  for (int i = tid; i < 32 * 16; i += 256) sP2[i] = ldf(P2, i, m);
  if (tid < 16) sP3[tid] = ldf(P3, tid, m);
  if (tid < 32) sb1[tid] = ldf(pb1, tid, m);
  if (tid < 16) sb2[tid] = ldf(pb2, tid, m);
  if (tid == 0) sb3 = ldf(pb3, 0, m);
  __syncthreads();

  int idx = blockIdx.x * 256 + tid;  // [0, 2P)
  int s, d;
  if (idx < PP) { s = pos_src[idx]; d = pos_dst[idx]; }
  else          { s = neg_src[idx - PP]; d = neg_dst[idx - PP]; }

  const u16* hs = g_Hf16 + s * 64;
  const u16* hd = g_Hf16 + d * 64;
  float z1[32];
#pragma unroll
  for (int j = 0; j < 32; ++j) z1[j] = sb1[j];
#pragma unroll
  for (int kk = 0; kk < 8; ++kk) {
    short8v h8s = *(const short8v*)(hs + kk * 8);
    short8v h8d = *(const short8v*)(hd + kk * 8);
#pragma unroll
    for (int t = 0; t < 8; ++t) {
      float zk = bf2f((u16)h8s[t]) * bf2f((u16)h8d[t]);
      const float* p1r = sP1 + (kk * 8 + t) * 32;
#pragma unroll
      for (int j = 0; j < 32; ++j) z1[j] += zk * p1r[j];
    }
  }
#pragma unroll
  for (int j = 0; j < 32; ++j) z1[j] = z1[j] > 0.f ? z1[j] : 0.2f * z1[j];
  float z2[16];
#pragma unroll
  for (int j = 0; j < 16; ++j) {
    float a = sb2[j];
#pragma unroll
    for (int k = 0; k < 32; ++k) a += z1[k] * sP2[k * 16 + j];
    z2[j] = a > 0.f ? a : 0.2f * a;
  }
  float o = sb3;
#pragma unroll
  for (int k = 0; k < 16; ++k) o += z2[k] * sP3[k];
  if (m) ((float*)out)[idx] = o;
  else   ((u16*)out)[idx] = f2bf(o);
}

// ------------------------------------------------------------------- launch
extern "C" void kernel_launch(void* const* d_in, const int* in_sizes, int n_in,
                              void* d_out, int out_size, void* d_ws, size_t ws_size,
                              hipStream_t stream) {
  const u16* x       = (const u16*)d_in[0];
  const int* src     = (const int*)d_in[1];
  const int* dst     = (const int*)d_in[2];
  const void* w_edge = d_in[3];
  const int* pos_src = (const int*)d_in[4];
  const int* pos_dst = (const int*)d_in[5];
  const int* neg_src = (const int*)d_in[6];
  const int* neg_dst = (const int*)d_in[7];
  const void* W1 = d_in[8];
  const void* b1 = d_in[9];
  const void* W2 = d_in[10];
  const void* b2 = d_in[11];
  const void* W3 = d_in[12];
  const void* b3 = d_in[13];
  const void* P1  = d_in[14];
  const void* pb1 = d_in[15];
  const void* P2  = d_in[16];
  const void* pb2 = d_in[17];
  const void* P3  = d_in[18];
  const void* pb3 = d_in[19];
  (void)d_ws; (void)ws_size; (void)in_sizes; (void)n_in; (void)out_size;

  // --- probe + pre-conversion + CSR build ---
  probe_dtype_kernel<<<1, 256, 0, stream>>>(x);
  convert_x_kernel<<<(NN * 64 + 255) / 256, 256, 0, stream>>>(x);
  convert_w_kernel<128, 1><<<32, 256, 0, stream>>>(W1);
  convert_w_kernel<128, 2><<<32, 256, 0, stream>>>(W2);
  convert_w_kernel<64, 3><<<16, 256, 0, stream>>>(W3);
  zero_deg_kernel<<<(NN + 255) / 256, 256, 0, stream>>>();
  count_deg_kernel<<<(EE + 255) / 256, 256, 0, stream>>>(dst);
  deg_partial_kernel<<<NB, 256, 0, stream>>>();
  scan_bsum_kernel<<<1, 256, 0, stream>>>();
  rowptr_kernel<<<NB, 256, 0, stream>>>();
  fill_csr_kernel<<<(EE + 255) / 256, 256, 0, stream>>>(src, dst, w_edge);

  int gHop = 25000;  // 4 feature-chunk phases x 6250 node-groups
  int gGemm = (NN + 127) / 128;

  // --- Layer 1: f0 = x(bf16) ---
  hop_kernel<0, 5><<<gHop, 256, 0, stream>>>();
  hop_kernel<5, 6><<<gHop, 256, 0, stream>>>();
  hop_kernel<6, 7><<<gHop, 256, 0, stream>>>();
  gemm_kernel<128, true, 0, 3, 1><<<gGemm, 256, 0, stream>>>(b1, nullptr);

  // --- Layer 2: f0 = Hn0 ---
  hop_kernel<3, 5><<<gHop, 256, 0, stream>>>();
  hop_kernel<5, 6><<<gHop, 256, 0, stream>>>();
  hop_kernel<6, 7><<<gHop, 256, 0, stream>>>();
  gemm_kernel<128, true, 3, 4, 2><<<gGemm, 256, 0, stream>>>(b2, nullptr);

  // --- Layer 3: f0 = Hn1, no relu, writes g_Hf16 + out h-region ---
  hop_kernel<4, 5><<<gHop, 256, 0, stream>>>();
  hop_kernel<5, 6><<<gHop, 256, 0, stream>>>();
  hop_kernel<6, 7><<<gHop, 256, 0, stream>>>();
  gemm_kernel<64, false, 4, 0, 3><<<gGemm, 256, 0, stream>>>(b3, d_out);

  // --- Predictor (pos+neg fused) ---
  predictor_kernel<<<(2 * PP) / 256, 256, 0, stream>>>(pos_src, pos_dst, neg_src, neg_dst,
                                                       P1, pb1, P2, pb2, P3, pb3, d_out);
}

// Round 10
// 1019.824 us; speedup vs baseline: 1.1701x; 1.1701x over previous
//
#include <hip/hip_runtime.h>
#include <hip/hip_bf16.h>

typedef unsigned short u16;
typedef unsigned int u32;
typedef short short8v __attribute__((ext_vector_type(8)));
typedef float f32x4 __attribute__((ext_vector_type(4)));

#define NN 50000
#define EE 800000
#define PP 65536
#define NB 196  // ceil(NN/256)

// ---- static device workspace. RULE (r3): device-global addresses never cross
// the host/device boundary — kernels resolve them via compile-time IDs.
// Feature buffers are CHUNK-MAJOR [4][NN][32] (r9 post-mortem): a 32-feature
// slice is contiguous 3.2 MB -> L2-resident per XCD during its phase. Row-major
// slices (64-B fragments @ stride 256) waste half of each 128-B line and alias
// to half the sets -> can never be resident.
__device__ __align__(256) float g_deg_norm[NN];
__device__ __align__(256) int   g_row_ptr[NN + 1];
__device__ __align__(256) int   g_deg[NN];
__device__ __align__(256) int   g_rank[EE];        // intra-row rank from count_deg
__device__ __align__(256) int   g_bsum[256];
__device__ __align__(256) int   g_boff[256];
__device__ __align__(256) int2  g_ecw[EE];         // (col, w-bits) fused pair
__device__ __align__(256) u16   g_X16[NN * 128];   // chunk-major [4][NN][32]
__device__ __align__(256) u16   g_H1[NN * 128];    // chunk-major
__device__ __align__(256) u16   g_H2[NN * 128];
__device__ __align__(256) u16   g_H3[NN * 128];
__device__ __align__(256) u16   g_Hn0[NN * 128];   // chunk-major
__device__ __align__(256) u16   g_Hn1[NN * 128];
__device__ __align__(256) u16   g_Hf16[NN * 64];   // row-major (predictor only)
__device__ __align__(256) u16   g_Bf1[512 * 128];  // W in MFMA B-fragment order
__device__ __align__(256) u16   g_Bf2[512 * 128];
__device__ __align__(256) u16   g_Bf3[512 * 64];
__device__ int g_f32mode;  // 1 if harness float tensors are float32, 0 if bf16

__device__ __forceinline__ float bf2f(u16 u) {
  union { u32 i; float f; } v;
  v.i = ((u32)u) << 16;
  return v.f;
}
__device__ __forceinline__ u16 f2bf(float f) {
  u32 x = __float_as_uint(f);
  u32 r = (x + 0x7fffu + ((x >> 16) & 1u)) >> 16;  // RNE
  return (u16)r;
}
__device__ __forceinline__ float ldf(const void* p, int i, int m) {
  return m ? ((const float*)p)[i] : bf2f(((const u16*)p)[i]);
}

// buffer IDs: 0 = X16, 3 = Hn0, 4 = Hn1, 5 = H1, 6 = H2, 7 = H3
template <int ID>
__device__ __forceinline__ u16* sel_buf() {
  if (ID == 0) return g_X16;
  if (ID == 3) return g_Hn0;
  if (ID == 4) return g_Hn1;
  if (ID == 5) return g_H1;
  if (ID == 6) return g_H2;
  return g_H3;
}
template <int ID>
__device__ __forceinline__ u16* sel_bf() {
  if (ID == 1) return g_Bf1;
  if (ID == 2) return g_Bf2;
  return g_Bf3;
}

// -------------------------------------------------------------- dtype probe
__global__ void probe_dtype_kernel(const u16* __restrict__ x) {
  __shared__ int cnt;
  if (threadIdx.x == 0) cnt = 0;
  __syncthreads();
  int c = 0;
  for (int i = threadIdx.x; i < 2048; i += 256) {
    u16 u = x[2 * i];
    int e = (u >> 7) & 0xFF;
    if (e >= 0x8F) c++;
  }
  atomicAdd(&cnt, c);
  __syncthreads();
  if (threadIdx.x == 0) g_f32mode = (cnt > 64) ? 1 : 0;
}

// ------------------------------------------- x -> bf16, chunk-major [4][NN][32]
__global__ void convert_x_kernel(const void* __restrict__ x) {
  int m = g_f32mode;
  int i = blockIdx.x * 256 + threadIdx.x;  // pair index: n*64 + fp
  if (i >= NN * 64) return;
  int n = i >> 6, fp = i & 63;             // fp = feature-pair 0..63
  int chunk = fp >> 4;
  u32 lo = f2bf(ldf(x, n * 128 + 2 * fp, m));
  u32 hi = f2bf(ldf(x, n * 128 + 2 * fp + 1, m));
  ((u32*)g_X16)[chunk * (NN * 16) + n * 16 + (fp & 15)] = lo | (hi << 16);
}

// --------------------------------------------- W -> fragment-ordered bf16
template <int FOUT, int BF_ID>
__global__ void convert_w_kernel(const void* __restrict__ W) {
  constexpr int NT = FOUT / 16;
  int m = g_f32mode;
  int t = blockIdx.x * 256 + threadIdx.x;
  if (t >= 1024 * NT) return;
  int lane = t & 63;
  int rest = t >> 6;
  int nt = rest % NT;
  int s = (rest / NT) % 4;
  int kc = rest / (NT * 4);
  int kbase = kc * 128 + s * 32 + ((lane >> 4) << 3);
  int n = nt * 16 + (lane & 15);
  u16* dst = sel_bf<BF_ID>() + (size_t)t * 8;
#pragma unroll
  for (int j = 0; j < 8; ++j) dst[j] = f2bf(ldf(W, (kbase + j) * FOUT + n, m));
}

// ---------------------------------------------------------------- CSR build
__global__ void zero_deg_kernel() {
  int i = blockIdx.x * blockDim.x + threadIdx.x;
  if (i < NN) g_deg[i] = 0;
}
__global__ void count_deg_kernel(const int* __restrict__ dst) {
  int e = blockIdx.x * blockDim.x + threadIdx.x;
  if (e < EE) g_rank[e] = atomicAdd(&g_deg[dst[e]], 1);
}
__global__ __launch_bounds__(256) void deg_partial_kernel() {
  __shared__ int ws[4];
  int b = blockIdx.x, t = threadIdx.x;
  int i = b * 256 + t;
  int v = (i < NN) ? g_deg[i] : 0;
  if (i < NN) g_deg_norm[i] = rsqrtf((float)(v > 0 ? v : 1));
  int x = v;
#pragma unroll
  for (int off = 1; off < 64; off <<= 1) x += __shfl_xor(x, off, 64);
  if ((t & 63) == 0) ws[t >> 6] = x;
  __syncthreads();
  if (t == 0) g_bsum[b] = ws[0] + ws[1] + ws[2] + ws[3];
}
__global__ __launch_bounds__(256) void scan_bsum_kernel() {
  __shared__ int ws[4];
  int t = threadIdx.x;
  int v = (t < NB) ? g_bsum[t] : 0;
  int x = v;
#pragma unroll
  for (int off = 1; off < 64; off <<= 1) {
    int y = __shfl_up(x, off, 64);
    if ((t & 63) >= off) x += y;
  }
  if ((t & 63) == 63) ws[t >> 6] = x;
  __syncthreads();
  int wp = 0;
  if (t >= 64) wp += ws[0];
  if (t >= 128) wp += ws[1];
  if (t >= 192) wp += ws[2];
  if (t < NB) g_boff[t] = wp + x - v;  // exclusive
}
__global__ __launch_bounds__(256) void rowptr_kernel() {
  __shared__ int ws[4];
  int b = blockIdx.x, t = threadIdx.x;
  int i = b * 256 + t;
  int v = (i < NN) ? g_deg[i] : 0;
  int x = v;
#pragma unroll
  for (int off = 1; off < 64; off <<= 1) {
    int y = __shfl_up(x, off, 64);
    if ((t & 63) >= off) x += y;
  }
  if ((t & 63) == 63) ws[t >> 6] = x;
  __syncthreads();
  int wp = g_boff[b];
  if (t >= 64) wp += ws[0];
  if (t >= 128) wp += ws[1];
  if (t >= 192) wp += ws[2];
  if (i < NN) g_row_ptr[i] = wp + x - v;
  if (b == 0 && t == 0) g_row_ptr[NN] = EE;
}
__global__ void fill_csr_kernel(const int* __restrict__ src, const int* __restrict__ dst,
                                const void* __restrict__ w_edge) {
  int m = g_f32mode;
  int e = blockIdx.x * blockDim.x + threadIdx.x;
  if (e >= EE) return;
  int d = dst[e], s = src[e];
  int slot = g_row_ptr[d] + g_rank[e];  // no atomic
  float w = ldf(w_edge, e, m) * g_deg_norm[s];
  g_ecw[slot] = make_int2(s, __float_as_int(w));
}

// ------------------------------------------------------------------- one hop
// out[n][f] = deg_norm[n] * sum_e w[e] * in[col[e]][f]
// Phase-major feature chunking over CHUNK-MAJOR buffers: chunk = blockIdx/6250;
// whole GPU works one contiguous 3.2-MB slice at a time -> slice L2-resident in
// every XCD (no workgroup->XCD mapping assumption). Half-wave (32 lanes x u16)
// per node: each edge-gather = one 64-B segment of the resident slice.
template <int IN_ID, int OUT_ID>
__global__ __launch_bounds__(256) void hop_kernel() {
  int bi = blockIdx.x;           // 25000 blocks = 4 phases x 6250
  int chunk = bi / 6250;
  int g = bi - chunk * 6250;
  int tid = threadIdx.x;
  int hw = tid >> 5;             // half-wave 0..7
  int l = tid & 31;
  int n = g * 8 + hw;            // 6250*8 = 50000 exactly
  const u16* in = sel_buf<IN_ID>() + (size_t)chunk * NN * 32 + l;
  int beg = g_row_ptr[n], end = g_row_ptr[n + 1];
  float a[8];
#pragma unroll
  for (int i = 0; i < 8; ++i) a[i] = 0.f;
  int e = beg;
  for (; e + 8 <= end; e += 8) {
    u32 pw = ((const u32*)(g_ecw + e))[l & 15];  // 8 pairs = 16 words, 64 B
#pragma unroll
    for (int i = 0; i < 8; ++i) {
      int si = __shfl((int)pw, 2 * i, 16);
      float wi = __int_as_float(__shfl((int)pw, 2 * i + 1, 16));
      a[i] += wi * bf2f(in[si * 32]);
    }
  }
  for (; e < end; ++e) {
    int2 p = g_ecw[e];
    a[0] += __int_as_float(p.y) * bf2f(in[p.x * 32]);
  }
  float s = ((a[0] + a[1]) + (a[2] + a[3])) + ((a[4] + a[5]) + (a[6] + a[7]));
  u16 r = f2bf(s * g_deg_norm[n]);
  __builtin_nontemporal_store(r, sel_buf<OUT_ID>() + (size_t)chunk * NN * 32 + n * 32 + l);
}

// ------------------------------------------------------------------ MFMA GEMM
// C(M x FOUT) = [f0 | H1 | H2 | H3] (Mx512, chunk-major) @ B + bias, opt ReLU.
// Block = 128 rows x ALL FOUT cols. K-chunk s of 32 == feature chunk s:
// A-load = base + s*NN*32 + row*32 + quad*8 (16-B aligned dwordx4).
template <int FOUT, bool RELU, int A0_ID, int C_ID, int BF_ID>
__global__ __launch_bounds__(256) void gemm_kernel(const void* __restrict__ bias,
                                                   void* __restrict__ outp) {
  constexpr int NT = FOUT / 16;
  const u16* Bf = sel_bf<BF_ID>();
  int tid = threadIdx.x;
  int lane = tid & 63, wv = tid >> 6;
  int quad = lane >> 4, arow = lane & 15;
  int mbase = blockIdx.x * 128 + wv * 32;
  bool gu0 = mbase < NN;
  bool gu1 = (mbase + 16) < NN;
  if (!gu0) return;  // no barriers in kernel -> safe
  int row0 = mbase + arow, row1 = mbase + 16 + arow;

  f32x4 acc[2][NT];
#pragma unroll
  for (int mt = 0; mt < 2; ++mt)
#pragma unroll
    for (int nt = 0; nt < NT; ++nt) acc[mt][nt] = (f32x4){0.f, 0.f, 0.f, 0.f};

#pragma unroll
  for (int kc = 0; kc < 4; ++kc) {
    const u16* base = (kc == 0) ? sel_buf<A0_ID>() : (kc == 1) ? g_H1 : (kc == 2) ? g_H2 : g_H3;
#pragma unroll
    for (int s = 0; s < 4; ++s) {
      const u16* sb = base + (size_t)s * NN * 32 + quad * 8;
      short8v av0 = *(const short8v*)(sb + row0 * 32);
      short8v av1;
      if (gu1) av1 = *(const short8v*)(sb + row1 * 32);
      const u16* bp = Bf + (size_t)(((kc * 4 + s) * NT) * 64 + lane) * 8;
#pragma unroll
      for (int nt = 0; nt < NT; ++nt) {
        short8v b = *(const short8v*)(bp + nt * 64 * 8);
        acc[0][nt] = __builtin_amdgcn_mfma_f32_16x16x32_bf16(av0, b, acc[0][nt], 0, 0, 0);
        if (gu1) acc[1][nt] = __builtin_amdgcn_mfma_f32_16x16x32_bf16(av1, b, acc[1][nt], 0, 0, 0);
      }
    }
  }

  int m = g_f32mode;
  float bn[NT];
#pragma unroll
  for (int nt = 0; nt < NT; ++nt) bn[nt] = ldf(bias, nt * 16 + arow, m);
#pragma unroll
  for (int mt = 0; mt < 2; ++mt) {
    if (mt == 1 && !gu1) break;
#pragma unroll
    for (int i = 0; i < 4; ++i) {
      int row = mbase + mt * 16 + quad * 4 + i;  // C/D: col=lane&15, row=quad*4+reg
#pragma unroll
      for (int nt = 0; nt < NT; ++nt) {
        float v = acc[mt][nt][i] + bn[nt];
        if (RELU) v = v > 0.f ? v : 0.f;
        if (C_ID == 0) {
          int ci = row * FOUT + nt * 16 + arow;          // row-major (predictor/out)
          g_Hf16[ci] = f2bf(v);
          if (m) ((float*)outp)[2 * PP + ci] = v;
          else   ((u16*)outp)[2 * PP + ci] = f2bf(v);
        } else {
          // chunk-major: chunk = nt/2, offset (nt&1)*16 + arow
          size_t ci = (size_t)(nt >> 1) * NN * 32 + row * 32 + (nt & 1) * 16 + arow;
          sel_buf<C_ID>()[ci] = f2bf(v);
        }
      }
    }
  }
}

// ------------------------------------------------------------------ predictor
__global__ __launch_bounds__(256) void predictor_kernel(
    const int* __restrict__ pos_src, const int* __restrict__ pos_dst,
    const int* __restrict__ neg_src, const int* __restrict__ neg_dst,
    const void* __restrict__ P1, const void* __restrict__ pb1, const void* __restrict__ P2,
    const void* __restrict__ pb2, const void* __restrict__ P3, const void* __restrict__ pb3,
    void* __restrict__ out) {
  __shared__ float sP1[64 * 32];
  __shared__ float sP2[32 * 16];
  __shared__ float sP3[16];
  __shared__ float sb1[32], sb2[16], sb3;
  int m = g_f32mode;
  int tid = threadIdx.x;
  for (int i = tid; i < 64 * 32; i += 256) sP1[i] = ldf(P1, i, m);
  for (int i = tid; i < 32 * 16; i += 256) sP2[i] = ldf(P2, i, m);
  if (tid < 16) sP3[tid] = ldf(P3, tid, m);
  if (tid < 32) sb1[tid] = ldf(pb1, tid, m);
  if (tid < 16) sb2[tid] = ldf(pb2, tid, m);
  if (tid == 0) sb3 = ldf(pb3, 0, m);
  __syncthreads();

  int idx = blockIdx.x * 256 + tid;  // [0, 2P)
  int s, d;
  if (idx < PP) { s = pos_src[idx]; d = pos_dst[idx]; }
  else          { s = neg_src[idx - PP]; d = neg_dst[idx - PP]; }

  const u16* hs = g_Hf16 + s * 64;
  const u16* hd = g_Hf16 + d * 64;
  float z1[32];
#pragma unroll
  for (int j = 0; j < 32; ++j) z1[j] = sb1[j];
#pragma unroll
  for (int kk = 0; kk < 8; ++kk) {
    short8v h8s = *(const short8v*)(hs + kk * 8);
    short8v h8d = *(const short8v*)(hd + kk * 8);
#pragma unroll
    for (int t = 0; t < 8; ++t) {
      float zk = bf2f((u16)h8s[t]) * bf2f((u16)h8d[t]);
      const float* p1r = sP1 + (kk * 8 + t) * 32;
#pragma unroll
      for (int j = 0; j < 32; ++j) z1[j] += zk * p1r[j];
    }
  }
#pragma unroll
  for (int j = 0; j < 32; ++j) z1[j] = z1[j] > 0.f ? z1[j] : 0.2f * z1[j];
  float z2[16];
#pragma unroll
  for (int j = 0; j < 16; ++j) {
    float a = sb2[j];
#pragma unroll
    for (int k = 0; k < 32; ++k) a += z1[k] * sP2[k * 16 + j];
    z2[j] = a > 0.f ? a : 0.2f * a;
  }
  float o = sb3;
#pragma unroll
  for (int k = 0; k < 16; ++k) o += z2[k] * sP3[k];
  if (m) ((float*)out)[idx] = o;
  else   ((u16*)out)[idx] = f2bf(o);
}

// ------------------------------------------------------------------- launch
extern "C" void kernel_launch(void* const* d_in, const int* in_sizes, int n_in,
                              void* d_out, int out_size, void* d_ws, size_t ws_size,
                              hipStream_t stream) {
  const u16* x       = (const u16*)d_in[0];
  const int* src     = (const int*)d_in[1];
  const int* dst     = (const int*)d_in[2];
  const void* w_edge = d_in[3];
  const int* pos_src = (const int*)d_in[4];
  const int* pos_dst = (const int*)d_in[5];
  const int* neg_src = (const int*)d_in[6];
  const int* neg_dst = (const int*)d_in[7];
  const void* W1 = d_in[8];
  const void* b1 = d_in[9];
  const void* W2 = d_in[10];
  const void* b2 = d_in[11];
  const void* W3 = d_in[12];
  const void* b3 = d_in[13];
  const void* P1  = d_in[14];
  const void* pb1 = d_in[15];
  const void* P2  = d_in[16];
  const void* pb2 = d_in[17];
  const void* P3  = d_in[18];
  const void* pb3 = d_in[19];
  (void)d_ws; (void)ws_size; (void)in_sizes; (void)n_in; (void)out_size;

  // --- probe + pre-conversion + CSR build ---
  probe_dtype_kernel<<<1, 256, 0, stream>>>(x);
  convert_x_kernel<<<(NN * 64 + 255) / 256, 256, 0, stream>>>(x);
  convert_w_kernel<128, 1><<<32, 256, 0, stream>>>(W1);
  convert_w_kernel<128, 2><<<32, 256, 0, stream>>>(W2);
  convert_w_kernel<64, 3><<<16, 256, 0, stream>>>(W3);
  zero_deg_kernel<<<(NN + 255) / 256, 256, 0, stream>>>();
  count_deg_kernel<<<(EE + 255) / 256, 256, 0, stream>>>(dst);
  deg_partial_kernel<<<NB, 256, 0, stream>>>();
  scan_bsum_kernel<<<1, 256, 0, stream>>>();
  rowptr_kernel<<<NB, 256, 0, stream>>>();
  fill_csr_kernel<<<(EE + 255) / 256, 256, 0, stream>>>(src, dst, w_edge);

  int gHop = 25000;  // 4 feature-chunk phases x 6250 node-groups
  int gGemm = (NN + 127) / 128;

  // --- Layer 1: f0 = x(bf16) ---
  hop_kernel<0, 5><<<gHop, 256, 0, stream>>>();
  hop_kernel<5, 6><<<gHop, 256, 0, stream>>>();
  hop_kernel<6, 7><<<gHop, 256, 0, stream>>>();
  gemm_kernel<128, true, 0, 3, 1><<<gGemm, 256, 0, stream>>>(b1, nullptr);

  // --- Layer 2: f0 = Hn0 ---
  hop_kernel<3, 5><<<gHop, 256, 0, stream>>>();
  hop_kernel<5, 6><<<gHop, 256, 0, stream>>>();
  hop_kernel<6, 7><<<gHop, 256, 0, stream>>>();
  gemm_kernel<128, true, 3, 4, 2><<<gGemm, 256, 0, stream>>>(b2, nullptr);

  // --- Layer 3: f0 = Hn1, no relu, writes g_Hf16 + out h-region ---
  hop_kernel<4, 5><<<gHop, 256, 0, stream>>>();
  hop_kernel<5, 6><<<gHop, 256, 0, stream>>>();
  hop_kernel<6, 7><<<gHop, 256, 0, stream>>>();
  gemm_kernel<64, false, 4, 0, 3><<<gGemm, 256, 0, stream>>>(b3, d_out);

  // --- Predictor (pos+neg fused) ---
  predictor_kernel<<<(2 * PP) / 256, 256, 0, stream>>>(pos_src, pos_dst, neg_src, neg_dst,
                                                       P1, pb1, P2, pb2, P3, pb3, d_out);
}

// Round 11
// 644.166 us; speedup vs baseline: 1.8524x; 1.5832x over previous
//
#include <hip/hip_runtime.h>
#include <hip/hip_bf16.h>

typedef unsigned short u16;
typedef unsigned int u32;
typedef short short8v __attribute__((ext_vector_type(8)));
typedef float f32x4 __attribute__((ext_vector_type(4)));

#define NN 50000
#define EE 800000
#define PP 65536
#define NB 196  // ceil(NN/256)

// ---- static device workspace. RULE (r3): device-global addresses never cross
// the host/device boundary — kernels resolve them via compile-time IDs.
// r10 post-mortem: chunked/phase hop structure (r8-r10) never beat the simple
// r7 full-wave row gather (4x requests + 4x edge-stream re-reads ate the L2
// residency gain) -> all feature buffers back to ROW-MAJOR [NN][128].
__device__ __align__(256) float g_deg_norm[NN];
__device__ __align__(256) int   g_row_ptr[NN + 1];
__device__ __align__(256) int   g_deg[NN];
__device__ __align__(256) int   g_rank[EE];        // intra-row rank from count_deg
__device__ __align__(256) int   g_bsum[256];
__device__ __align__(256) int   g_boff[256];
__device__ __align__(256) int2  g_ecw[EE];         // (col, w-bits) fused pair
__device__ __align__(256) u16   g_X16[NN * 128];   // x bf16, row-major
__device__ __align__(256) u16   g_H1[NN * 128];    // hop outputs, stride 128
__device__ __align__(256) u16   g_H2[NN * 128];
__device__ __align__(256) u16   g_H3[NN * 128];
__device__ __align__(256) u16   g_Hn0[NN * 128];
__device__ __align__(256) u16   g_Hn1[NN * 128];
__device__ __align__(256) u16   g_Hf16[NN * 64];   // final h (bf16), row-major
__device__ __align__(256) u16   g_Bf1[512 * 128];  // W in MFMA B-fragment order
__device__ __align__(256) u16   g_Bf2[512 * 128];
__device__ __align__(256) u16   g_Bf3[512 * 64];
__device__ __align__(256) u16   g_Pf1[4 * 64 * 8]; // P1 in B-frag order (2 kstep x 2 ntile)
__device__ int g_f32mode;  // 1 if harness float tensors are float32, 0 if bf16

__device__ __forceinline__ float bf2f(u16 u) {
  union { u32 i; float f; } v;
  v.i = ((u32)u) << 16;
  return v.f;
}
__device__ __forceinline__ u16 f2bf(float f) {
  u32 x = __float_as_uint(f);
  u32 r = (x + 0x7fffu + ((x >> 16) & 1u)) >> 16;  // RNE
  return (u16)r;
}
__device__ __forceinline__ float ldf(const void* p, int i, int m) {
  return m ? ((const float*)p)[i] : bf2f(((const u16*)p)[i]);
}

// buffer IDs: 0 = X16, 3 = Hn0, 4 = Hn1, 5 = H1, 6 = H2, 7 = H3 (stride 128)
template <int ID>
__device__ __forceinline__ u16* sel_buf() {
  if (ID == 0) return g_X16;
  if (ID == 3) return g_Hn0;
  if (ID == 4) return g_Hn1;
  if (ID == 5) return g_H1;
  if (ID == 6) return g_H2;
  return g_H3;
}
template <int ID>
__device__ __forceinline__ u16* sel_bf() {
  if (ID == 1) return g_Bf1;
  if (ID == 2) return g_Bf2;
  return g_Bf3;
}

// -------------------------------------------------------------- dtype probe
__global__ void probe_dtype_kernel(const u16* __restrict__ x) {
  __shared__ int cnt;
  if (threadIdx.x == 0) cnt = 0;
  __syncthreads();
  int c = 0;
  for (int i = threadIdx.x; i < 2048; i += 256) {
    u16 u = x[2 * i];
    int e = (u >> 7) & 0xFF;
    if (e >= 0x8F) c++;
  }
  atomicAdd(&cnt, c);
  __syncthreads();
  if (threadIdx.x == 0) g_f32mode = (cnt > 64) ? 1 : 0;
}

// ---------------------------------------------------------- x -> bf16 convert
__global__ void convert_x_kernel(const void* __restrict__ x) {
  int m = g_f32mode;
  int i = blockIdx.x * 256 + threadIdx.x;  // u32-pair index
  if (i >= NN * 64) return;
  u32 lo = f2bf(ldf(x, 2 * i, m));
  u32 hi = f2bf(ldf(x, 2 * i + 1, m));
  ((u32*)g_X16)[i] = lo | (hi << 16);
}

// --------------------------------------------- W -> fragment-ordered bf16
template <int FOUT, int BF_ID>
__global__ void convert_w_kernel(const void* __restrict__ W) {
  constexpr int NT = FOUT / 16;
  int m = g_f32mode;
  int t = blockIdx.x * 256 + threadIdx.x;
  if (t >= 1024 * NT) return;
  int lane = t & 63;
  int rest = t >> 6;
  int nt = rest % NT;
  int s = (rest / NT) % 4;
  int kc = rest / (NT * 4);
  int kbase = kc * 128 + s * 32 + ((lane >> 4) << 3);
  int n = nt * 16 + (lane & 15);
  u16* dst = sel_bf<BF_ID>() + (size_t)t * 8;
#pragma unroll
  for (int j = 0; j < 8; ++j) dst[j] = f2bf(ldf(W, (kbase + j) * FOUT + n, m));
}

// ----------------------------------- P1 (64x32) -> B-fragment order for MFMA
// frag f = kstep*2 + ntile; entry [lane][j] = P1[kstep*32 + quad*8 + j][ntile*16 + arow]
__global__ void convert_p_kernel(const void* __restrict__ P1) {
  int m = g_f32mode;
  int t = threadIdx.x;  // 256 threads, 1 block
  int f = t >> 6, lane = t & 63;
  int ks = f >> 1, nt = f & 1;
  int quad = lane >> 4, arow = lane & 15;
#pragma unroll
  for (int j = 0; j < 8; ++j)
    g_Pf1[(size_t)t * 8 + j] = f2bf(ldf(P1, (ks * 32 + quad * 8 + j) * 32 + nt * 16 + arow, m));
}

// ---------------------------------------------------------------- CSR build
__global__ void zero_deg_kernel() {
  int i = blockIdx.x * blockDim.x + threadIdx.x;
  if (i < NN) g_deg[i] = 0;
}
__global__ void count_deg_kernel(const int* __restrict__ dst) {
  int e = blockIdx.x * blockDim.x + threadIdx.x;
  if (e < EE) g_rank[e] = atomicAdd(&g_deg[dst[e]], 1);
}
__global__ __launch_bounds__(256) void deg_partial_kernel() {
  __shared__ int ws[4];
  int b = blockIdx.x, t = threadIdx.x;
  int i = b * 256 + t;
  int v = (i < NN) ? g_deg[i] : 0;
  if (i < NN) g_deg_norm[i] = rsqrtf((float)(v > 0 ? v : 1));
  int x = v;
#pragma unroll
  for (int off = 1; off < 64; off <<= 1) x += __shfl_xor(x, off, 64);
  if ((t & 63) == 0) ws[t >> 6] = x;
  __syncthreads();
  if (t == 0) g_bsum[b] = ws[0] + ws[1] + ws[2] + ws[3];
}
__global__ __launch_bounds__(256) void scan_bsum_kernel() {
  __shared__ int ws[4];
  int t = threadIdx.x;
  int v = (t < NB) ? g_bsum[t] : 0;
  int x = v;
#pragma unroll
  for (int off = 1; off < 64; off <<= 1) {
    int y = __shfl_up(x, off, 64);
    if ((t & 63) >= off) x += y;
  }
  if ((t & 63) == 63) ws[t >> 6] = x;
  __syncthreads();
  int wp = 0;
  if (t >= 64) wp += ws[0];
  if (t >= 128) wp += ws[1];
  if (t >= 192) wp += ws[2];
  if (t < NB) g_boff[t] = wp + x - v;  // exclusive
}
__global__ __launch_bounds__(256) void rowptr_kernel() {
  __shared__ int ws[4];
  int b = blockIdx.x, t = threadIdx.x;
  int i = b * 256 + t;
  int v = (i < NN) ? g_deg[i] : 0;
  int x = v;
#pragma unroll
  for (int off = 1; off < 64; off <<= 1) {
    int y = __shfl_up(x, off, 64);
    if ((t & 63) >= off) x += y;
  }
  if ((t & 63) == 63) ws[t >> 6] = x;
  __syncthreads();
  int wp = g_boff[b];
  if (t >= 64) wp += ws[0];
  if (t >= 128) wp += ws[1];
  if (t >= 192) wp += ws[2];
  if (i < NN) g_row_ptr[i] = wp + x - v;
  if (b == 0 && t == 0) g_row_ptr[NN] = EE;
}
__global__ void fill_csr_kernel(const int* __restrict__ src, const int* __restrict__ dst,
                                const void* __restrict__ w_edge) {
  int m = g_f32mode;
  int e = blockIdx.x * blockDim.x + threadIdx.x;
  if (e >= EE) return;
  int d = dst[e], s = src[e];
  int slot = g_row_ptr[d] + g_rank[e];  // no atomic
  float w = ldf(w_edge, e, m) * g_deg_norm[s];
  g_ecw[slot] = make_int2(s, __float_as_int(w));
}

// ------------------------------------------------------------------- one hop
// out[n][f] = deg_norm[n] * sum_e w[e] * in[col[e]][f]
// r7-proven: one wave per node (4/block); lane = 2 features; 8/4/1 unroll with
// 16 independent accumulators -> 8 outstanding 256-B row gathers per wave.
template <int IN_ID, int OUT_ID>
__global__ __launch_bounds__(256) void hop_kernel() {
  int n = blockIdx.x * 4 + (threadIdx.x >> 6);
  if (n >= NN) return;
  int f2 = threadIdx.x & 63;
  const u16* inf = sel_buf<IN_ID>() + 2 * f2;
  int beg = g_row_ptr[n], end = g_row_ptr[n + 1];
  float a0[8], a1[8];
#pragma unroll
  for (int i = 0; i < 8; ++i) { a0[i] = 0.f; a1[i] = 0.f; }
  int e = beg;
  for (; e + 8 <= end; e += 8) {
    int2 p[8];
#pragma unroll
    for (int i = 0; i < 8; ++i) p[i] = g_ecw[e + i];
    u32 u[8];
#pragma unroll
    for (int i = 0; i < 8; ++i) u[i] = *(const u32*)(inf + p[i].x * 128);
#pragma unroll
    for (int i = 0; i < 8; ++i) {
      float w = __int_as_float(p[i].y);
      a0[i] += w * bf2f((u16)u[i]);
      a1[i] += w * bf2f((u16)(u[i] >> 16));
    }
  }
  for (; e + 4 <= end; e += 4) {
    int2 p[4];
#pragma unroll
    for (int i = 0; i < 4; ++i) p[i] = g_ecw[e + i];
    u32 u[4];
#pragma unroll
    for (int i = 0; i < 4; ++i) u[i] = *(const u32*)(inf + p[i].x * 128);
#pragma unroll
    for (int i = 0; i < 4; ++i) {
      float w = __int_as_float(p[i].y);
      a0[i] += w * bf2f((u16)u[i]);
      a1[i] += w * bf2f((u16)(u[i] >> 16));
    }
  }
  for (; e < end; ++e) {
    int2 p = g_ecw[e];
    u32 u = *(const u32*)(inf + p.x * 128);
    a0[0] += __int_as_float(p.y) * bf2f((u16)u);
    a1[0] += __int_as_float(p.y) * bf2f((u16)(u >> 16));
  }
  float s0 = ((a0[0] + a0[1]) + (a0[2] + a0[3])) + ((a0[4] + a0[5]) + (a0[6] + a0[7]));
  float s1 = ((a1[0] + a1[1]) + (a1[2] + a1[3])) + ((a1[4] + a1[5]) + (a1[6] + a1[7]));
  float dn = g_deg_norm[n];
  *(u32*)(sel_buf<OUT_ID>() + n * 128 + 2 * f2) =
      (u32)f2bf(s0 * dn) | ((u32)f2bf(s1 * dn) << 16);
}

// ------------------------------------------------------------------ MFMA GEMM
// C(M x FOUT) = [f0 | H1 | H2 | H3] (Mx512, row-major) @ B + bias, opt ReLU.
// Block = 128 rows x ALL FOUT cols (A read exactly once). 4 waves x 32 rows.
template <int FOUT, bool RELU, int A0_ID, int C_ID, int BF_ID>
__global__ __launch_bounds__(256) void gemm_kernel(const void* __restrict__ bias,
                                                   void* __restrict__ outp) {
  constexpr int NT = FOUT / 16;
  const u16* Bf = sel_bf<BF_ID>();
  int tid = threadIdx.x;
  int lane = tid & 63, wv = tid >> 6;
  int quad = lane >> 4, arow = lane & 15;
  int mbase = blockIdx.x * 128 + wv * 32;
  bool gu0 = mbase < NN;
  bool gu1 = (mbase + 16) < NN;
  if (!gu0) return;  // no barriers in kernel -> safe
  int row0 = mbase + arow, row1 = mbase + 16 + arow;

  f32x4 acc[2][NT];
#pragma unroll
  for (int mt = 0; mt < 2; ++mt)
#pragma unroll
    for (int nt = 0; nt < NT; ++nt) acc[mt][nt] = (f32x4){0.f, 0.f, 0.f, 0.f};

#pragma unroll
  for (int kc = 0; kc < 4; ++kc) {
    const u16* base = (kc == 0) ? sel_buf<A0_ID>() : (kc == 1) ? g_H1 : (kc == 2) ? g_H2 : g_H3;
#pragma unroll
    for (int s = 0; s < 4; ++s) {
      int ko = s * 32 + quad * 8;
      short8v av0 = *(const short8v*)(base + row0 * 128 + ko);
      short8v av1;
      if (gu1) av1 = *(const short8v*)(base + row1 * 128 + ko);
      const u16* bp = Bf + (size_t)(((kc * 4 + s) * NT) * 64 + lane) * 8;
#pragma unroll
      for (int nt = 0; nt < NT; ++nt) {
        short8v b = *(const short8v*)(bp + nt * 64 * 8);
        acc[0][nt] = __builtin_amdgcn_mfma_f32_16x16x32_bf16(av0, b, acc[0][nt], 0, 0, 0);
        if (gu1) acc[1][nt] = __builtin_amdgcn_mfma_f32_16x16x32_bf16(av1, b, acc[1][nt], 0, 0, 0);
      }
    }
  }

  int m = g_f32mode;
  float bn[NT];
#pragma unroll
  for (int nt = 0; nt < NT; ++nt) bn[nt] = ldf(bias, nt * 16 + arow, m);
#pragma unroll
  for (int mt = 0; mt < 2; ++mt) {
    if (mt == 1 && !gu1) break;
#pragma unroll
    for (int i = 0; i < 4; ++i) {
      int row = mbase + mt * 16 + quad * 4 + i;  // C/D: col=lane&15, row=quad*4+reg
#pragma unroll
      for (int nt = 0; nt < NT; ++nt) {
        float v = acc[mt][nt][i] + bn[nt];
        if (RELU) v = v > 0.f ? v : 0.f;
        int ci = row * FOUT + nt * 16 + arow;
        if (C_ID == 0) {
          g_Hf16[ci] = f2bf(v);
          if (m) ((float*)outp)[2 * PP + ci] = v;
          else   ((u16*)outp)[2 * PP + ci] = f2bf(v);
        } else {
          sel_buf<C_ID>()[ci] = f2bf(v);
        }
      }
    }
  }
}

// ------------------------------------------------------------------ predictor
// MFMA predictor (r10 post-mortem: one-pair-per-thread was gather-latency
// bound at 85 us, VGPR 152, occ 11%). One wave = 16 pairs: lane (quad,arow)
// loads h[s[arow]], h[d[arow]] directly in MFMA A-layout (A[m=lane&15]
// [k=quad*8+j]), z=hs*hd in bf16, 4 MFMAs -> layer1 (64->32). Layer 2/3 via
// per-wave LDS transpose (stride 33, bank-safe) + scalar, width-64 shuffles.
__global__ __launch_bounds__(256) void predictor_kernel(
    const int* __restrict__ pos_src, const int* __restrict__ pos_dst,
    const int* __restrict__ neg_src, const int* __restrict__ neg_dst,
    const void* __restrict__ pb1, const void* __restrict__ P2,
    const void* __restrict__ pb2, const void* __restrict__ P3, const void* __restrict__ pb3,
    void* __restrict__ out) {
  __shared__ float sP2[32 * 16];
  __shared__ float sb1[32], sb2[16], sP3[16];
  __shared__ float sb3;
  __shared__ float zt[4][16][33];
  int m = g_f32mode;
  int tid = threadIdx.x;
  for (int i = tid; i < 512; i += 256) sP2[i] = ldf(P2, i, m);
  if (tid < 32) sb1[tid] = ldf(pb1, tid, m);
  if (tid < 16) sb2[tid] = ldf(pb2, tid, m);
  if (tid < 16) sP3[tid] = ldf(P3, tid, m);
  if (tid == 0) sb3 = ldf(pb3, 0, m);
  __syncthreads();

  int wv = tid >> 6, lane = tid & 63;
  int quad = lane >> 4, arow = lane & 15;
  int base = (blockIdx.x * 4 + wv) * 16;
  int idx = base + arow;
  int s, d;
  if (idx < PP) { s = pos_src[idx]; d = pos_dst[idx]; }      // PP%16==0 -> wave-uniform
  else          { s = neg_src[idx - PP]; d = neg_dst[idx - PP]; }

  // z A-fragments (2 k-steps)
  const u16* hs = g_Hf16 + s * 64 + quad * 8;
  const u16* hd = g_Hf16 + d * 64 + quad * 8;
  short8v zf[2];
#pragma unroll
  for (int ks = 0; ks < 2; ++ks) {
    short8v a = *(const short8v*)(hs + ks * 32);
    short8v b = *(const short8v*)(hd + ks * 32);
#pragma unroll
    for (int j = 0; j < 8; ++j)
      ((u16*)&zf[ks])[j] = f2bf(bf2f((u16)a[j]) * bf2f((u16)b[j]));
  }
  // layer 1: z(16x64) @ P1(64x32) -> 4 MFMAs
  f32x4 acc[2];
  acc[0] = (f32x4){0.f, 0.f, 0.f, 0.f};
  acc[1] = (f32x4){0.f, 0.f, 0.f, 0.f};
#pragma unroll
  for (int ks = 0; ks < 2; ++ks) {
#pragma unroll
    for (int nt = 0; nt < 2; ++nt) {
      short8v bfr = *(const short8v*)(g_Pf1 + (size_t)((ks * 2 + nt) * 64 + lane) * 8);
      acc[nt] = __builtin_amdgcn_mfma_f32_16x16x32_bf16(zf[ks], bfr, acc[nt], 0, 0, 0);
    }
  }
  // bias + leaky, transpose C-layout (pair=quad*4+i, col=nt*16+arow) into LDS
#pragma unroll
  for (int nt = 0; nt < 2; ++nt) {
    float bn = sb1[nt * 16 + arow];
#pragma unroll
    for (int i = 0; i < 4; ++i) {
      float v = acc[nt][i] + bn;
      zt[wv][quad * 4 + i][nt * 16 + arow] = v > 0.f ? v : 0.2f * v;
    }
  }
  __syncthreads();
  // layer 2: pair = arow, outputs j2 = quad*4..quad*4+3
  float z2[4];
#pragma unroll
  for (int jj = 0; jj < 4; ++jj) z2[jj] = sb2[quad * 4 + jj];
  const float* zrow = &zt[wv][arow][0];
#pragma unroll
  for (int c = 0; c < 32; ++c) {
    float zc = zrow[c];
#pragma unroll
    for (int jj = 0; jj < 4; ++jj) z2[jj] += zc * sP2[c * 16 + quad * 4 + jj];
  }
  // layer 3 partial + cross-quad reduce (lanes 16 apart hold same pair)
  float o = 0.f;
#pragma unroll
  for (int jj = 0; jj < 4; ++jj) {
    float v = z2[jj] > 0.f ? z2[jj] : 0.2f * z2[jj];
    o += v * sP3[quad * 4 + jj];
  }
  o += __shfl_xor(o, 16, 64);
  o += __shfl_xor(o, 32, 64);
  o += sb3;
  if (quad == 0) {
    if (m) ((float*)out)[idx] = o;
    else   ((u16*)out)[idx] = f2bf(o);
  }
}

// ------------------------------------------------------------------- launch
extern "C" void kernel_launch(void* const* d_in, const int* in_sizes, int n_in,
                              void* d_out, int out_size, void* d_ws, size_t ws_size,
                              hipStream_t stream) {
  const u16* x       = (const u16*)d_in[0];
  const int* src     = (const int*)d_in[1];
  const int* dst     = (const int*)d_in[2];
  const void* w_edge = d_in[3];
  const int* pos_src = (const int*)d_in[4];
  const int* pos_dst = (const int*)d_in[5];
  const int* neg_src = (const int*)d_in[6];
  const int* neg_dst = (const int*)d_in[7];
  const void* W1 = d_in[8];
  const void* b1 = d_in[9];
  const void* W2 = d_in[10];
  const void* b2 = d_in[11];
  const void* W3 = d_in[12];
  const void* b3 = d_in[13];
  const void* P1  = d_in[14];
  const void* pb1 = d_in[15];
  const void* P2  = d_in[16];
  const void* pb2 = d_in[17];
  const void* P3  = d_in[18];
  const void* pb3 = d_in[19];
  (void)d_ws; (void)ws_size; (void)in_sizes; (void)n_in; (void)out_size;

  // --- probe + pre-conversion + CSR build ---
  probe_dtype_kernel<<<1, 256, 0, stream>>>(x);
  convert_x_kernel<<<(NN * 64 + 255) / 256, 256, 0, stream>>>(x);
  convert_w_kernel<128, 1><<<32, 256, 0, stream>>>(W1);
  convert_w_kernel<128, 2><<<32, 256, 0, stream>>>(W2);
  convert_w_kernel<64, 3><<<16, 256, 0, stream>>>(W3);
  convert_p_kernel<<<1, 256, 0, stream>>>(P1);
  zero_deg_kernel<<<(NN + 255) / 256, 256, 0, stream>>>();
  count_deg_kernel<<<(EE + 255) / 256, 256, 0, stream>>>(dst);
  deg_partial_kernel<<<NB, 256, 0, stream>>>();
  scan_bsum_kernel<<<1, 256, 0, stream>>>();
  rowptr_kernel<<<NB, 256, 0, stream>>>();
  fill_csr_kernel<<<(EE + 255) / 256, 256, 0, stream>>>(src, dst, w_edge);

  int gHop = (NN + 3) / 4;
  int gGemm = (NN + 127) / 128;

  // --- Layer 1: f0 = x(bf16) ---
  hop_kernel<0, 5><<<gHop, 256, 0, stream>>>();
  hop_kernel<5, 6><<<gHop, 256, 0, stream>>>();
  hop_kernel<6, 7><<<gHop, 256, 0, stream>>>();
  gemm_kernel<128, true, 0, 3, 1><<<gGemm, 256, 0, stream>>>(b1, nullptr);

  // --- Layer 2: f0 = Hn0 ---
  hop_kernel<3, 5><<<gHop, 256, 0, stream>>>();
  hop_kernel<5, 6><<<gHop, 256, 0, stream>>>();
  hop_kernel<6, 7><<<gHop, 256, 0, stream>>>();
  gemm_kernel<128, true, 3, 4, 2><<<gGemm, 256, 0, stream>>>(b2, nullptr);

  // --- Layer 3: f0 = Hn1, no relu, writes g_Hf16 + out h-region ---
  hop_kernel<4, 5><<<gHop, 256, 0, stream>>>();
  hop_kernel<5, 6><<<gHop, 256, 0, stream>>>();
  hop_kernel<6, 7><<<gHop, 256, 0, stream>>>();
  gemm_kernel<64, false, 4, 0, 3><<<gGemm, 256, 0, stream>>>(b3, d_out);

  // --- Predictor (pos+neg fused, MFMA) ---
  predictor_kernel<<<(2 * PP) / (4 * 16), 256, 0, stream>>>(pos_src, pos_dst, neg_src, neg_dst,
                                                            pb1, P2, pb2, P3, pb3, d_out);
}

// Round 12
// 568.608 us; speedup vs baseline: 2.0986x; 1.1329x over previous
//
#include <hip/hip_runtime.h>
#include <hip/hip_bf16.h>

typedef unsigned short u16;
typedef unsigned int u32;
typedef short short8v __attribute__((ext_vector_type(8)));
typedef float f32x4 __attribute__((ext_vector_type(4)));

#define NN 50000
#define EE 800000
#define PP 65536
#define NB 196  // ceil(NN/256)

// ---- static device workspace. RULE (r3): device-global addresses never cross
// the host/device boundary — kernels resolve them via compile-time IDs.
__device__ __align__(256) float g_deg_norm[NN];
__device__ __align__(256) int   g_row_ptr[NN + 1];
__device__ __align__(256) int   g_deg[NN];
__device__ __align__(256) int   g_rank[EE];        // intra-row rank from count_deg
__device__ __align__(256) int   g_bsum[256];
__device__ __align__(256) int   g_boff[256];
__device__ __align__(256) u32   g_ecwp[EE];        // packed edge: col(16b) | w_bf16(16b)
__device__ __align__(256) u16   g_X16[NN * 128];   // x bf16, row-major
__device__ __align__(256) u16   g_H1[NN * 128];    // hop outputs, stride 128
__device__ __align__(256) u16   g_H2[NN * 128];
__device__ __align__(256) u16   g_H3[NN * 128];
__device__ __align__(256) u16   g_Hn0[NN * 128];
__device__ __align__(256) u16   g_Hn1[NN * 128];
__device__ __align__(256) u16   g_Hf16[NN * 64];   // final h (bf16), row-major
__device__ __align__(256) u16   g_Bf1[512 * 128];  // W in MFMA B-fragment order
__device__ __align__(256) u16   g_Bf2[512 * 128];
__device__ __align__(256) u16   g_Bf3[512 * 64];
__device__ __align__(256) u16   g_Pf1[4 * 64 * 8]; // P1 in B-frag order
__device__ int g_f32mode;  // 1 if harness float tensors are float32, 0 if bf16

__device__ __forceinline__ float bf2f(u16 u) {
  union { u32 i; float f; } v;
  v.i = ((u32)u) << 16;
  return v.f;
}
__device__ __forceinline__ u16 f2bf(float f) {
  u32 x = __float_as_uint(f);
  u32 r = (x + 0x7fffu + ((x >> 16) & 1u)) >> 16;  // RNE
  return (u16)r;
}
__device__ __forceinline__ float ldf(const void* p, int i, int m) {
  return m ? ((const float*)p)[i] : bf2f(((const u16*)p)[i]);
}

// buffer IDs: 0 = X16, 3 = Hn0, 4 = Hn1, 5 = H1, 6 = H2, 7 = H3 (stride 128)
template <int ID>
__device__ __forceinline__ u16* sel_buf() {
  if (ID == 0) return g_X16;
  if (ID == 3) return g_Hn0;
  if (ID == 4) return g_Hn1;
  if (ID == 5) return g_H1;
  if (ID == 6) return g_H2;
  return g_H3;
}
template <int ID>
__device__ __forceinline__ u16* sel_bf() {
  if (ID == 1) return g_Bf1;
  if (ID == 2) return g_Bf2;
  return g_Bf3;
}

// -------------------------------------------------------------- dtype probe
__global__ void probe_dtype_kernel(const u16* __restrict__ x) {
  __shared__ int cnt;
  if (threadIdx.x == 0) cnt = 0;
  __syncthreads();
  int c = 0;
  for (int i = threadIdx.x; i < 2048; i += 256) {
    u16 u = x[2 * i];
    int e = (u >> 7) & 0xFF;
    if (e >= 0x8F) c++;
  }
  atomicAdd(&cnt, c);
  __syncthreads();
  if (threadIdx.x == 0) g_f32mode = (cnt > 64) ? 1 : 0;
}

// ---------------------------------------------------------- x -> bf16 convert
__global__ void convert_x_kernel(const void* __restrict__ x) {
  int m = g_f32mode;
  int i = blockIdx.x * 256 + threadIdx.x;  // u32-pair index
  if (i >= NN * 64) return;
  u32 lo = f2bf(ldf(x, 2 * i, m));
  u32 hi = f2bf(ldf(x, 2 * i + 1, m));
  ((u32*)g_X16)[i] = lo | (hi << 16);
}

// --------------------------------------------- W -> fragment-ordered bf16
template <int FOUT, int BF_ID>
__global__ void convert_w_kernel(const void* __restrict__ W) {
  constexpr int NT = FOUT / 16;
  int m = g_f32mode;
  int t = blockIdx.x * 256 + threadIdx.x;
  if (t >= 1024 * NT) return;
  int lane = t & 63;
  int rest = t >> 6;
  int nt = rest % NT;
  int s = (rest / NT) % 4;
  int kc = rest / (NT * 4);
  int kbase = kc * 128 + s * 32 + ((lane >> 4) << 3);
  int n = nt * 16 + (lane & 15);
  u16* dst = sel_bf<BF_ID>() + (size_t)t * 8;
#pragma unroll
  for (int j = 0; j < 8; ++j) dst[j] = f2bf(ldf(W, (kbase + j) * FOUT + n, m));
}

// ----------------------------------- P1 (64x32) -> B-fragment order for MFMA
__global__ void convert_p_kernel(const void* __restrict__ P1) {
  int m = g_f32mode;
  int t = threadIdx.x;  // 256 threads, 1 block
  int f = t >> 6, lane = t & 63;
  int ks = f >> 1, nt = f & 1;
  int quad = lane >> 4, arow = lane & 15;
#pragma unroll
  for (int j = 0; j < 8; ++j)
    g_Pf1[(size_t)t * 8 + j] = f2bf(ldf(P1, (ks * 32 + quad * 8 + j) * 32 + nt * 16 + arow, m));
}

// ---------------------------------------------------------------- CSR build
__global__ void zero_deg_kernel() {
  int i = blockIdx.x * blockDim.x + threadIdx.x;
  if (i < NN) g_deg[i] = 0;
}
__global__ void count_deg_kernel(const int* __restrict__ dst) {
  int e = blockIdx.x * blockDim.x + threadIdx.x;
  if (e < EE) g_rank[e] = atomicAdd(&g_deg[dst[e]], 1);
}
__global__ __launch_bounds__(256) void deg_partial_kernel() {
  __shared__ int ws[4];
  int b = blockIdx.x, t = threadIdx.x;
  int i = b * 256 + t;
  int v = (i < NN) ? g_deg[i] : 0;
  if (i < NN) g_deg_norm[i] = rsqrtf((float)(v > 0 ? v : 1));
  int x = v;
#pragma unroll
  for (int off = 1; off < 64; off <<= 1) x += __shfl_xor(x, off, 64);
  if ((t & 63) == 0) ws[t >> 6] = x;
  __syncthreads();
  if (t == 0) g_bsum[b] = ws[0] + ws[1] + ws[2] + ws[3];
}
__global__ __launch_bounds__(256) void scan_bsum_kernel() {
  __shared__ int ws[4];
  int t = threadIdx.x;
  int v = (t < NB) ? g_bsum[t] : 0;
  int x = v;
#pragma unroll
  for (int off = 1; off < 64; off <<= 1) {
    int y = __shfl_up(x, off, 64);
    if ((t & 63) >= off) x += y;
  }
  if ((t & 63) == 63) ws[t >> 6] = x;
  __syncthreads();
  int wp = 0;
  if (t >= 64) wp += ws[0];
  if (t >= 128) wp += ws[1];
  if (t >= 192) wp += ws[2];
  if (t < NB) g_boff[t] = wp + x - v;  // exclusive
}
__global__ __launch_bounds__(256) void rowptr_kernel() {
  __shared__ int ws[4];
  int b = blockIdx.x, t = threadIdx.x;
  int i = b * 256 + t;
  int v = (i < NN) ? g_deg[i] : 0;
  int x = v;
#pragma unroll
  for (int off = 1; off < 64; off <<= 1) {
    int y = __shfl_up(x, off, 64);
    if ((t & 63) >= off) x += y;
  }
  if ((t & 63) == 63) ws[t >> 6] = x;
  __syncthreads();
  int wp = g_boff[b];
  if (t >= 64) wp += ws[0];
  if (t >= 128) wp += ws[1];
  if (t >= 192) wp += ws[2];
  if (i < NN) g_row_ptr[i] = wp + x - v;
  if (b == 0 && t == 0) g_row_ptr[NN] = EE;
}
// packed edge record: col fits 16 bits (NN < 65536), w as bf16 in high 16.
// Halves scattered-store line footprint vs int2 (r11: 52 MB write-allocate).
__global__ void fill_csr_kernel(const int* __restrict__ src, const int* __restrict__ dst,
                                const void* __restrict__ w_edge) {
  int m = g_f32mode;
  int e = blockIdx.x * blockDim.x + threadIdx.x;
  if (e >= EE) return;
  int d = dst[e], s = src[e];
  int slot = g_row_ptr[d] + g_rank[e];  // no atomic
  float w = ldf(w_edge, e, m) * g_deg_norm[s];
  g_ecwp[slot] = (u32)s | ((u32)f2bf(w) << 16);
}

// ------------------------------------------------------------------- one hop
// out[n][f] = deg_norm[n] * sum_e w[e] * in[col[e]][f]
// one wave per node (4/block); lane = 2 features; 8/4/1 unroll with 16
// independent accumulators -> 8 outstanding 256-B row gathers per wave.
template <int IN_ID, int OUT_ID>
__global__ __launch_bounds__(256) void hop_kernel() {
  int n = blockIdx.x * 4 + (threadIdx.x >> 6);
  if (n >= NN) return;
  int f2 = threadIdx.x & 63;
  const u16* inf = sel_buf<IN_ID>() + 2 * f2;
  int beg = g_row_ptr[n], end = g_row_ptr[n + 1];
  float a0[8], a1[8];
#pragma unroll
  for (int i = 0; i < 8; ++i) { a0[i] = 0.f; a1[i] = 0.f; }
  int e = beg;
  for (; e + 8 <= end; e += 8) {
    u32 p[8];
#pragma unroll
    for (int i = 0; i < 8; ++i) p[i] = g_ecwp[e + i];
    u32 u[8];
#pragma unroll
    for (int i = 0; i < 8; ++i) u[i] = *(const u32*)(inf + (p[i] & 0xFFFFu) * 128);
#pragma unroll
    for (int i = 0; i < 8; ++i) {
      float w = bf2f((u16)(p[i] >> 16));
      a0[i] += w * bf2f((u16)u[i]);
      a1[i] += w * bf2f((u16)(u[i] >> 16));
    }
  }
  for (; e + 4 <= end; e += 4) {
    u32 p[4];
#pragma unroll
    for (int i = 0; i < 4; ++i) p[i] = g_ecwp[e + i];
    u32 u[4];
#pragma unroll
    for (int i = 0; i < 4; ++i) u[i] = *(const u32*)(inf + (p[i] & 0xFFFFu) * 128);
#pragma unroll
    for (int i = 0; i < 4; ++i) {
      float w = bf2f((u16)(p[i] >> 16));
      a0[i] += w * bf2f((u16)u[i]);
      a1[i] += w * bf2f((u16)(u[i] >> 16));
    }
  }
  for (; e < end; ++e) {
    u32 p = g_ecwp[e];
    u32 u = *(const u32*)(inf + (p & 0xFFFFu) * 128);
    float w = bf2f((u16)(p >> 16));
    a0[0] += w * bf2f((u16)u);
    a1[0] += w * bf2f((u16)(u >> 16));
  }
  float s0 = ((a0[0] + a0[1]) + (a0[2] + a0[3])) + ((a0[4] + a0[5]) + (a0[6] + a0[7]));
  float s1 = ((a1[0] + a1[1]) + (a1[2] + a1[3])) + ((a1[4] + a1[5]) + (a1[6] + a1[7]));
  float dn = g_deg_norm[n];
  *(u32*)(sel_buf<OUT_ID>() + n * 128 + 2 * f2) =
      (u32)f2bf(s0 * dn) | ((u32)f2bf(s1 * dn) << 16);
}

// ------------------------------------------------------------------ MFMA GEMM
// C(M x FOUT) = [f0 | H1 | H2 | H3] (Mx512, row-major) @ B + bias, opt ReLU.
// r11 post-mortem: 128-row blocks -> 391 blocks = 1.5/CU, occupancy 14.6%,
// latency-bound (MfmaUtil 5%). Now 64 rows/block (wave = ONE 16-row m-tile),
// grid 782 -> ~12 waves/CU. A still read exactly once.
template <int FOUT, bool RELU, int A0_ID, int C_ID, int BF_ID>
__global__ __launch_bounds__(256) void gemm_kernel(const void* __restrict__ bias,
                                                   void* __restrict__ outp) {
  constexpr int NT = FOUT / 16;
  const u16* Bf = sel_bf<BF_ID>();
  int tid = threadIdx.x;
  int lane = tid & 63, wv = tid >> 6;
  int quad = lane >> 4, arow = lane & 15;
  int mbase = blockIdx.x * 64 + wv * 16;
  if (mbase >= NN) return;  // no barriers in kernel -> safe (NN % 16 == 0)
  int row0 = mbase + arow;

  f32x4 acc[NT];
#pragma unroll
  for (int nt = 0; nt < NT; ++nt) acc[nt] = (f32x4){0.f, 0.f, 0.f, 0.f};

#pragma unroll
  for (int kc = 0; kc < 4; ++kc) {
    const u16* base = (kc == 0) ? sel_buf<A0_ID>() : (kc == 1) ? g_H1 : (kc == 2) ? g_H2 : g_H3;
#pragma unroll
    for (int s = 0; s < 4; ++s) {
      int ko = s * 32 + quad * 8;
      short8v av = *(const short8v*)(base + row0 * 128 + ko);
      const u16* bp = Bf + (size_t)(((kc * 4 + s) * NT) * 64 + lane) * 8;
#pragma unroll
      for (int nt = 0; nt < NT; ++nt) {
        short8v b = *(const short8v*)(bp + nt * 64 * 8);
        acc[nt] = __builtin_amdgcn_mfma_f32_16x16x32_bf16(av, b, acc[nt], 0, 0, 0);
      }
    }
  }

  int m = g_f32mode;
  float bn[NT];
#pragma unroll
  for (int nt = 0; nt < NT; ++nt) bn[nt] = ldf(bias, nt * 16 + arow, m);
#pragma unroll
  for (int i = 0; i < 4; ++i) {
    int row = mbase + quad * 4 + i;  // C/D: col=lane&15, row=quad*4+reg
#pragma unroll
    for (int nt = 0; nt < NT; ++nt) {
      float v = acc[nt][i] + bn[nt];
      if (RELU) v = v > 0.f ? v : 0.f;
      int ci = row * FOUT + nt * 16 + arow;
      if (C_ID == 0) {
        g_Hf16[ci] = f2bf(v);
        if (m) ((float*)outp)[2 * PP + ci] = v;
        else   ((u16*)outp)[2 * PP + ci] = f2bf(v);
      } else {
        sel_buf<C_ID>()[ci] = f2bf(v);
      }
    }
  }
}

// ------------------------------------------------------------------ predictor
// MFMA predictor (r11-proven). One wave = 16 pairs.
__global__ __launch_bounds__(256) void predictor_kernel(
    const int* __restrict__ pos_src, const int* __restrict__ pos_dst,
    const int* __restrict__ neg_src, const int* __restrict__ neg_dst,
    const void* __restrict__ pb1, const void* __restrict__ P2,
    const void* __restrict__ pb2, const void* __restrict__ P3, const void* __restrict__ pb3,
    void* __restrict__ out) {
  __shared__ float sP2[32 * 16];
  __shared__ float sb1[32], sb2[16], sP3[16];
  __shared__ float sb3;
  __shared__ float zt[4][16][33];
  int m = g_f32mode;
  int tid = threadIdx.x;
  for (int i = tid; i < 512; i += 256) sP2[i] = ldf(P2, i, m);
  if (tid < 32) sb1[tid] = ldf(pb1, tid, m);
  if (tid < 16) sb2[tid] = ldf(pb2, tid, m);
  if (tid < 16) sP3[tid] = ldf(P3, tid, m);
  if (tid == 0) sb3 = ldf(pb3, 0, m);
  __syncthreads();

  int wv = tid >> 6, lane = tid & 63;
  int quad = lane >> 4, arow = lane & 15;
  int base = (blockIdx.x * 4 + wv) * 16;
  int idx = base + arow;
  int s, d;
  if (idx < PP) { s = pos_src[idx]; d = pos_dst[idx]; }  // PP%16==0 -> wave-uniform
  else          { s = neg_src[idx - PP]; d = neg_dst[idx - PP]; }

  const u16* hs = g_Hf16 + s * 64 + quad * 8;
  const u16* hd = g_Hf16 + d * 64 + quad * 8;
  short8v zf[2];
#pragma unroll
  for (int ks = 0; ks < 2; ++ks) {
    short8v a = *(const short8v*)(hs + ks * 32);
    short8v b = *(const short8v*)(hd + ks * 32);
#pragma unroll
    for (int j = 0; j < 8; ++j)
      ((u16*)&zf[ks])[j] = f2bf(bf2f((u16)a[j]) * bf2f((u16)b[j]));
  }
  f32x4 acc[2];
  acc[0] = (f32x4){0.f, 0.f, 0.f, 0.f};
  acc[1] = (f32x4){0.f, 0.f, 0.f, 0.f};
#pragma unroll
  for (int ks = 0; ks < 2; ++ks) {
#pragma unroll
    for (int nt = 0; nt < 2; ++nt) {
      short8v bfr = *(const short8v*)(g_Pf1 + (size_t)((ks * 2 + nt) * 64 + lane) * 8);
      acc[nt] = __builtin_amdgcn_mfma_f32_16x16x32_bf16(zf[ks], bfr, acc[nt], 0, 0, 0);
    }
  }
#pragma unroll
  for (int nt = 0; nt < 2; ++nt) {
    float bn = sb1[nt * 16 + arow];
#pragma unroll
    for (int i = 0; i < 4; ++i) {
      float v = acc[nt][i] + bn;
      zt[wv][quad * 4 + i][nt * 16 + arow] = v > 0.f ? v : 0.2f * v;
    }
  }
  __syncthreads();
  float z2[4];
#pragma unroll
  for (int jj = 0; jj < 4; ++jj) z2[jj] = sb2[quad * 4 + jj];
  const float* zrow = &zt[wv][arow][0];
#pragma unroll
  for (int c = 0; c < 32; ++c) {
    float zc = zrow[c];
#pragma unroll
    for (int jj = 0; jj < 4; ++jj) z2[jj] += zc * sP2[c * 16 + quad * 4 + jj];
  }
  float o = 0.f;
#pragma unroll
  for (int jj = 0; jj < 4; ++jj) {
    float v = z2[jj] > 0.f ? z2[jj] : 0.2f * z2[jj];
    o += v * sP3[quad * 4 + jj];
  }
  o += __shfl_xor(o, 16, 64);
  o += __shfl_xor(o, 32, 64);
  o += sb3;
  if (quad == 0) {
    if (m) ((float*)out)[idx] = o;
    else   ((u16*)out)[idx] = f2bf(o);
  }
}

// ------------------------------------------------------------------- launch
extern "C" void kernel_launch(void* const* d_in, const int* in_sizes, int n_in,
                              void* d_out, int out_size, void* d_ws, size_t ws_size,
                              hipStream_t stream) {
  const u16* x       = (const u16*)d_in[0];
  const int* src     = (const int*)d_in[1];
  const int* dst     = (const int*)d_in[2];
  const void* w_edge = d_in[3];
  const int* pos_src = (const int*)d_in[4];
  const int* pos_dst = (const int*)d_in[5];
  const int* neg_src = (const int*)d_in[6];
  const int* neg_dst = (const int*)d_in[7];
  const void* W1 = d_in[8];
  const void* b1 = d_in[9];
  const void* W2 = d_in[10];
  const void* b2 = d_in[11];
  const void* W3 = d_in[12];
  const void* b3 = d_in[13];
  const void* P1  = d_in[14];
  const void* pb1 = d_in[15];
  const void* P2  = d_in[16];
  const void* pb2 = d_in[17];
  const void* P3  = d_in[18];
  const void* pb3 = d_in[19];
  (void)d_ws; (void)ws_size; (void)in_sizes; (void)n_in; (void)out_size;

  // --- probe + pre-conversion + CSR build ---
  probe_dtype_kernel<<<1, 256, 0, stream>>>(x);
  convert_x_kernel<<<(NN * 64 + 255) / 256, 256, 0, stream>>>(x);
  convert_w_kernel<128, 1><<<32, 256, 0, stream>>>(W1);
  convert_w_kernel<128, 2><<<32, 256, 0, stream>>>(W2);
  convert_w_kernel<64, 3><<<16, 256, 0, stream>>>(W3);
  convert_p_kernel<<<1, 256, 0, stream>>>(P1);
  zero_deg_kernel<<<(NN + 255) / 256, 256, 0, stream>>>();
  count_deg_kernel<<<(EE + 255) / 256, 256, 0, stream>>>(dst);
  deg_partial_kernel<<<NB, 256, 0, stream>>>();
  scan_bsum_kernel<<<1, 256, 0, stream>>>();
  rowptr_kernel<<<NB, 256, 0, stream>>>();
  fill_csr_kernel<<<(EE + 255) / 256, 256, 0, stream>>>(src, dst, w_edge);

  int gHop = (NN + 3) / 4;
  int gGemm = (NN + 63) / 64;

  // --- Layer 1: f0 = x(bf16) ---
  hop_kernel<0, 5><<<gHop, 256, 0, stream>>>();
  hop_kernel<5, 6><<<gHop, 256, 0, stream>>>();
  hop_kernel<6, 7><<<gHop, 256, 0, stream>>>();
  gemm_kernel<128, true, 0, 3, 1><<<gGemm, 256, 0, stream>>>(b1, nullptr);

  // --- Layer 2: f0 = Hn0 ---
  hop_kernel<3, 5><<<gHop, 256, 0, stream>>>();
  hop_kernel<5, 6><<<gHop, 256, 0, stream>>>();
  hop_kernel<6, 7><<<gHop, 256, 0, stream>>>();
  gemm_kernel<128, true, 3, 4, 2><<<gGemm, 256, 0, stream>>>(b2, nullptr);

  // --- Layer 3: f0 = Hn1, no relu, writes g_Hf16 + out h-region ---
  hop_kernel<4, 5><<<gHop, 256, 0, stream>>>();
  hop_kernel<5, 6><<<gHop, 256, 0, stream>>>();
  hop_kernel<6, 7><<<gHop, 256, 0, stream>>>();
  gemm_kernel<64, false, 4, 0, 3><<<gGemm, 256, 0, stream>>>(b3, d_out);

  // --- Predictor (pos+neg fused, MFMA) ---
  predictor_kernel<<<(2 * PP) / (4 * 16), 256, 0, stream>>>(pos_src, pos_dst, neg_src, neg_dst,
                                                            pb1, P2, pb2, P3, pb3, d_out);
}